// Round 1
// baseline (1506.418 us; speedup 1.0000x reference)
//
#include <hip/hip_runtime.h>

#define NNODES 100000
#define DN 64
#define DIN 128
#define HID 128
#define TM 32          // nodes per block in MLP kernel
#define SA 132         // padded LDS stride for activation buffers (128 + 4)
#define SW 132         // padded LDS stride for 128-wide weight chunk
#define SW2 68         // padded LDS stride for 64-wide weight chunk

// ---------------------------------------------------------------------------
// Scatter: agg[col[e]] += edge_attr[e]  (one thread per (edge, 4-float chunk))
// ---------------------------------------------------------------------------
__global__ __launch_bounds__(256) void scatter_kernel(
    const float* __restrict__ ea, const int* __restrict__ col,
    float* __restrict__ agg, int n_edges) {
  int i = blockIdx.x * 256 + threadIdx.x;
  if (i >= n_edges * 16) return;
  int e = i >> 4;
  int c = (i & 15) << 2;
  int d = col[e];
  const float4 v = *(const float4*)(ea + (size_t)e * 64 + c);
  float* p = agg + (size_t)d * 64 + c;
  unsafeAtomicAdd(p + 0, v.x);
  unsafeAtomicAdd(p + 1, v.y);
  unsafeAtomicAdd(p + 2, v.z);
  unsafeAtomicAdd(p + 3, v.w);
}

// ---------------------------------------------------------------------------
// Fused MLP + LayerNorm + residual. One block = 32 nodes, 256 threads.
// Thread (tx=tid&15, ty=tid>>4) computes rows {2ty,2ty+1} x cols
// {4tx..4tx+3, 64+4tx..64+4tx+3} (layers 0/1) or {4tx..4tx+3} (layer 2).
// ---------------------------------------------------------------------------

// Macro (not function) so LDS address-space inference never sees a generic ptr.
#define LAYER128(Abuf, Hbuf, Wp, bp)                                           \
  {                                                                            \
    float acc0[8], acc1[8];                                                    \
    {                                                                          \
      float4 bl = *(const float4*)(bp + 4 * tx);                               \
      float4 bh = *(const float4*)(bp + 64 + 4 * tx);                          \
      acc0[0] = bl.x; acc0[1] = bl.y; acc0[2] = bl.z; acc0[3] = bl.w;          \
      acc0[4] = bh.x; acc0[5] = bh.y; acc0[6] = bh.z; acc0[7] = bh.w;          \
      for (int j = 0; j < 8; ++j) acc1[j] = acc0[j];                           \
    }                                                                          \
    for (int kc = 0; kc < 4; ++kc) {                                           \
      __syncthreads();                                                         \
      for (int i = tid; i < 32 * 32; i += 256) {                               \
        int kr = i >> 5;                                                       \
        int c = (i & 31) << 2;                                                 \
        *(float4*)(bufW + kr * SW + c) =                                       \
            *(const float4*)(Wp + (size_t)(kc * 32 + kr) * 128 + c);           \
      }                                                                        \
      __syncthreads();                                                         \
      _Pragma("unroll 8")                                                      \
      for (int k = 0; k < 32; ++k) {                                           \
        float a0 = Abuf[r0 * SA + kc * 32 + k];                                \
        float a1 = Abuf[r1 * SA + kc * 32 + k];                                \
        float4 w0 = *(const float4*)(bufW + k * SW + 4 * tx);                  \
        float4 w1 = *(const float4*)(bufW + k * SW + 64 + 4 * tx);             \
        acc0[0] += a0 * w0.x; acc0[1] += a0 * w0.y;                            \
        acc0[2] += a0 * w0.z; acc0[3] += a0 * w0.w;                            \
        acc0[4] += a0 * w1.x; acc0[5] += a0 * w1.y;                            \
        acc0[6] += a0 * w1.z; acc0[7] += a0 * w1.w;                            \
        acc1[0] += a1 * w0.x; acc1[1] += a1 * w0.y;                            \
        acc1[2] += a1 * w0.z; acc1[3] += a1 * w0.w;                            \
        acc1[4] += a1 * w1.x; acc1[5] += a1 * w1.y;                            \
        acc1[6] += a1 * w1.z; acc1[7] += a1 * w1.w;                            \
      }                                                                        \
    }                                                                          \
    __syncthreads();                                                           \
    for (int j = 0; j < 8; ++j) {                                              \
      acc0[j] = fmaxf(acc0[j], 0.f);                                           \
      acc1[j] = fmaxf(acc1[j], 0.f);                                           \
    }                                                                          \
    *(float4*)(Hbuf + r0 * SA + 4 * tx) =                                      \
        make_float4(acc0[0], acc0[1], acc0[2], acc0[3]);                       \
    *(float4*)(Hbuf + r0 * SA + 64 + 4 * tx) =                                 \
        make_float4(acc0[4], acc0[5], acc0[6], acc0[7]);                       \
    *(float4*)(Hbuf + r1 * SA + 4 * tx) =                                      \
        make_float4(acc1[0], acc1[1], acc1[2], acc1[3]);                       \
    *(float4*)(Hbuf + r1 * SA + 64 + 4 * tx) =                                 \
        make_float4(acc1[4], acc1[5], acc1[6], acc1[7]);                       \
    __syncthreads();                                                           \
  }

__global__ __launch_bounds__(256) void mlp_kernel(
    const float* __restrict__ x, const float* __restrict__ agg,
    const float* __restrict__ W0, const float* __restrict__ b0,
    const float* __restrict__ W1, const float* __restrict__ b1,
    const float* __restrict__ W2, const float* __restrict__ b2,
    const float* __restrict__ lng, const float* __restrict__ lnb,
    float* __restrict__ out) {
  __shared__ float bufA[TM * SA];
  __shared__ float bufB[TM * SA];
  __shared__ float bufW[32 * SW];

  const int tid = threadIdx.x;
  const int base = blockIdx.x * TM;   // 100000 = 3125 * 32, no remainder
  const int tx = tid & 15;
  const int ty = tid >> 4;
  const int r0 = 2 * ty;
  const int r1 = r0 + 1;

  // Stage concat(x, agg) -> bufA [32 x 128]
  for (int i = tid; i < TM * 32; i += 256) {
    int r = i >> 5;
    int c = (i & 31) << 2;
    int node = base + r;
    float4 v;
    if (c < 64) v = *(const float4*)(x + (size_t)node * 64 + c);
    else        v = *(const float4*)(agg + (size_t)node * 64 + (c - 64));
    *(float4*)(bufA + r * SA + c) = v;
  }
  __syncthreads();

  // Layer 0: bufA(128) -> bufB(128), relu
  LAYER128(bufA, bufB, W0, b0)
  // Layer 1: bufB(128) -> bufA(128), relu
  LAYER128(bufB, bufA, W1, b1)

  // Layer 2: bufA(128) -> bufB(64), +b2, no relu
  {
    float acc0[4], acc1[4];
    {
      float4 bv = *(const float4*)(b2 + 4 * tx);
      acc0[0] = bv.x; acc0[1] = bv.y; acc0[2] = bv.z; acc0[3] = bv.w;
      for (int j = 0; j < 4; ++j) acc1[j] = acc0[j];
    }
    for (int kc = 0; kc < 4; ++kc) {
      __syncthreads();
      for (int i = tid; i < 32 * 16; i += 256) {
        int kr = i >> 4;
        int c = (i & 15) << 2;
        *(float4*)(bufW + kr * SW2 + c) =
            *(const float4*)(W2 + (size_t)(kc * 32 + kr) * 64 + c);
      }
      __syncthreads();
#pragma unroll 8
      for (int k = 0; k < 32; ++k) {
        float a0 = bufA[r0 * SA + kc * 32 + k];
        float a1 = bufA[r1 * SA + kc * 32 + k];
        float4 w = *(const float4*)(bufW + k * SW2 + 4 * tx);
        acc0[0] += a0 * w.x; acc0[1] += a0 * w.y;
        acc0[2] += a0 * w.z; acc0[3] += a0 * w.w;
        acc1[0] += a1 * w.x; acc1[1] += a1 * w.y;
        acc1[2] += a1 * w.z; acc1[3] += a1 * w.w;
      }
    }
    __syncthreads();
    *(float4*)(bufB + r0 * SA + 4 * tx) =
        make_float4(acc0[0], acc0[1], acc0[2], acc0[3]);
    *(float4*)(bufB + r1 * SA + 4 * tx) =
        make_float4(acc1[0], acc1[1], acc1[2], acc1[3]);
    __syncthreads();
  }

  // LayerNorm over 64 dims + residual. 8 threads per row.
  {
    const int row = tid >> 3;
    const int g = tid & 7;
    const int c0 = g * 8;
    float4 h0 = *(const float4*)(bufB + row * SA + c0);
    float4 h1 = *(const float4*)(bufB + row * SA + c0 + 4);
    float s  = h0.x + h0.y + h0.z + h0.w + h1.x + h1.y + h1.z + h1.w;
    float ss = h0.x * h0.x + h0.y * h0.y + h0.z * h0.z + h0.w * h0.w +
               h1.x * h1.x + h1.y * h1.y + h1.z * h1.z + h1.w * h1.w;
    s  += __shfl_xor(s, 1);  ss += __shfl_xor(ss, 1);
    s  += __shfl_xor(s, 2);  ss += __shfl_xor(ss, 2);
    s  += __shfl_xor(s, 4);  ss += __shfl_xor(ss, 4);
    float mu = s * 0.015625f;                  // /64
    float var = ss * 0.015625f - mu * mu;
    float rs = rsqrtf(var + 1e-5f);
    int node = base + row;
    float4 g0 = *(const float4*)(lng + c0);
    float4 g1 = *(const float4*)(lng + c0 + 4);
    float4 e0 = *(const float4*)(lnb + c0);
    float4 e1 = *(const float4*)(lnb + c0 + 4);
    float4 x0 = *(const float4*)(x + (size_t)node * 64 + c0);
    float4 x1 = *(const float4*)(x + (size_t)node * 64 + c0 + 4);
    float4 o0, o1;
    o0.x = (h0.x - mu) * rs * g0.x + e0.x + x0.x;
    o0.y = (h0.y - mu) * rs * g0.y + e0.y + x0.y;
    o0.z = (h0.z - mu) * rs * g0.z + e0.z + x0.z;
    o0.w = (h0.w - mu) * rs * g0.w + e0.w + x0.w;
    o1.x = (h1.x - mu) * rs * g1.x + e1.x + x1.x;
    o1.y = (h1.y - mu) * rs * g1.y + e1.y + x1.y;
    o1.z = (h1.z - mu) * rs * g1.z + e1.z + x1.z;
    o1.w = (h1.w - mu) * rs * g1.w + e1.w + x1.w;
    *(float4*)(out + (size_t)node * 64 + c0) = o0;
    *(float4*)(out + (size_t)node * 64 + c0 + 4) = o1;
  }
}

extern "C" void kernel_launch(void* const* d_in, const int* in_sizes, int n_in,
                              void* d_out, int out_size, void* d_ws, size_t ws_size,
                              hipStream_t stream) {
  const float* x  = (const float*)d_in[0];
  const int*   ei = (const int*)d_in[1];
  const float* ea = (const float*)d_in[2];
  const float* W0 = (const float*)d_in[3];
  const float* b0 = (const float*)d_in[4];
  const float* W1 = (const float*)d_in[5];
  const float* b1 = (const float*)d_in[6];
  const float* W2 = (const float*)d_in[7];
  const float* b2 = (const float*)d_in[8];
  const float* lg = (const float*)d_in[9];
  const float* lb = (const float*)d_in[10];
  float* out = (float*)d_out;
  float* agg = (float*)d_ws;   // [NNODES x 64] f32 scratch

  const int n_edges = in_sizes[2] / DN;       // 1,200,000
  const int* col = ei + n_edges;              // edge_index[1] (second row)

  hipMemsetAsync(agg, 0, (size_t)NNODES * DN * sizeof(float), stream);

  int total = n_edges * 16;
  scatter_kernel<<<(total + 255) / 256, 256, 0, stream>>>(ea, col, agg, n_edges);

  mlp_kernel<<<NNODES / TM, 256, 0, stream>>>(x, agg, W0, b0, W1, b1, W2, b2,
                                              lg, lb, out);
}

// Round 2
// 1105.898 us; speedup vs baseline: 1.3622x; 1.3622x over previous
//
#include <hip/hip_runtime.h>

#define NNODES 100000
#define NEDGES_MAX 1200000
#define DN 64
#define SROW 136   // act row stride in bf16 elems: 272B = 17*16B (aligned, 2-way banks)

typedef short bf16x8 __attribute__((ext_vector_type(8)));
typedef float f32x4 __attribute__((ext_vector_type(4)));

__device__ __forceinline__ unsigned short f2bf(float f) {
  unsigned int u = __float_as_uint(f);
  u = (u + 0x7fffu + ((u >> 16) & 1u)) >> 16;   // RNE
  return (unsigned short)u;
}

// ---------------------------------------------------------------------------
// CSR build: histogram -> scan -> bucket fill
// ---------------------------------------------------------------------------
__global__ __launch_bounds__(256) void hist_kernel(const int* __restrict__ col,
                                                   int* __restrict__ deg, int n) {
  int i = blockIdx.x * 256 + threadIdx.x;
  if (i < n) atomicAdd(&deg[col[i]], 1);
}

__global__ __launch_bounds__(1024) void scan_kernel(const int* __restrict__ deg,
                                                    int* __restrict__ row_ptr,
                                                    int* __restrict__ cursor) {
  __shared__ int ps[1024];
  const int t = threadIdx.x;
  const int CH = 98;                       // 98*1024 >= 100000
  int lo = t * CH;
  int hi = lo + CH; if (hi > NNODES) hi = NNODES;
  int s = 0;
  for (int i = lo; i < hi; ++i) s += deg[i];
  ps[t] = s;
  __syncthreads();
  for (int off = 1; off < 1024; off <<= 1) {
    int v = (t >= off) ? ps[t - off] : 0;
    __syncthreads();
    ps[t] += v;
    __syncthreads();
  }
  int run = ps[t] - s;                     // exclusive prefix
  for (int i = lo; i < hi; ++i) {
    row_ptr[i] = run;
    cursor[i] = run;
    run += deg[i];
  }
  if (t == 1023) row_ptr[NNODES] = ps[1023];
}

__global__ __launch_bounds__(256) void fill_kernel(const int* __restrict__ col,
                                                   int* __restrict__ cursor,
                                                   int* __restrict__ elist, int n) {
  int i = blockIdx.x * 256 + threadIdx.x;
  if (i < n) {
    int pos = atomicAdd(&cursor[col[i]], 1);
    elist[pos] = i;
  }
}

// ---------------------------------------------------------------------------
// Weight prep: convert fp32 weights to bf16 laid out in exact MFMA B-fragment
// order. Block (nc,kc) = 512 elems (1 KB): lane l holds W[kc*32+(l>>4)*8+j]
// [nc*16+(l&15)], j=0..7 contiguous. 5120 threads, one 8-elem lane-chunk each.
// ---------------------------------------------------------------------------
__global__ __launch_bounds__(256) void wprep_kernel(
    const float* __restrict__ W0, const float* __restrict__ W1,
    const float* __restrict__ W2, unsigned short* __restrict__ wp) {
  int t = blockIdx.x * 256 + threadIdx.x;
  if (t >= 5120) return;
  const float* W; int c, N, dstbase;
  if (t < 2048)      { W = W0; c = t;        N = 128; dstbase = 0; }
  else if (t < 4096) { W = W1; c = t - 2048; N = 128; dstbase = 16384; }
  else               { W = W2; c = t - 4096; N = 64;  dstbase = 32768; }
  int blk = c >> 6;           // (nc*4+kc)
  int lane = c & 63;
  int nc = blk >> 2, kc = blk & 3;
  int k0 = kc * 32 + (lane >> 4) * 8;
  int n  = nc * 16 + (lane & 15);
  unsigned short* dst = wp + dstbase + blk * 512 + lane * 8;
#pragma unroll
  for (int j = 0; j < 8; ++j) dst[j] = f2bf(W[(size_t)(k0 + j) * N + n]);
}

// ---------------------------------------------------------------------------
// Fused: gather(agg) + MLP(3 layers, bf16 MFMA) + LayerNorm + residual.
// One wave = 16 nodes. No __syncthreads: all LDS is wave-private.
// A-frag: A[m=lane&15][k=(lane>>4)*8+j]; B-frag preswizzled in wp;
// C/D: col=lane&15, row=(lane>>4)*4+reg.
// ---------------------------------------------------------------------------
__global__ __launch_bounds__(256) void fused_mlp(
    const float* __restrict__ x, const int* __restrict__ row_ptr,
    const int* __restrict__ elist, const float* __restrict__ ea,
    const unsigned short* __restrict__ wp,
    const float* __restrict__ b0, const float* __restrict__ b1,
    const float* __restrict__ b2, const float* __restrict__ lng,
    const float* __restrict__ lnb, float* __restrict__ out) {
  __shared__ unsigned short act[4 * 2 * 16 * SROW];

  const int tid = threadIdx.x;
  const int wid = tid >> 6;
  const int lane = tid & 63;
  const int gw = blockIdx.x * 4 + wid;
  if (gw >= NNODES / 16) return;           // 6250 waves exactly
  const int base = gw * 16;
  const int m = lane & 15;                 // row / out-col within fragment
  const int quad = lane >> 4;

  unsigned short* Abuf = act + (wid * 2 + 0) * 16 * SROW;
  unsigned short* Bbuf = act + (wid * 2 + 1) * 16 * SROW;

  // ---- stage concat(x, gathered agg) as bf16 into Abuf [16 x 128] ----
  for (int r = 0; r < 16; ++r) {
    int node = base + r;
    float xv = x[(size_t)node * 64 + lane];
    Abuf[r * SROW + lane] = f2bf(xv);
    int s = row_ptr[node], e = row_ptr[node + 1];
    float acc = 0.f;
    for (int i = s; i < e; ++i) {
      int ed = elist[i];
      acc += ea[(size_t)ed * 64 + lane];
    }
    Abuf[r * SROW + 64 + lane] = f2bf(acc);
  }

  bf16x8 af[4];

  // ---- Layer 0: Abuf -> Bbuf, N=128, ReLU ----
#pragma unroll
  for (int kc = 0; kc < 4; ++kc)
    af[kc] = *(const bf16x8*)(Abuf + m * SROW + kc * 32 + quad * 8);
#pragma unroll
  for (int nc = 0; nc < 8; ++nc) {
    float bv = b0[nc * 16 + m];
    f32x4 acc = {bv, bv, bv, bv};
#pragma unroll
    for (int kc = 0; kc < 4; ++kc) {
      bf16x8 bf = *(const bf16x8*)(wp + (nc * 4 + kc) * 512 + lane * 8);
      acc = __builtin_amdgcn_mfma_f32_16x16x32_bf16(af[kc], bf, acc, 0, 0, 0);
    }
    int col = nc * 16 + m;
#pragma unroll
    for (int r2 = 0; r2 < 4; ++r2)
      Bbuf[(quad * 4 + r2) * SROW + col] = f2bf(fmaxf(acc[r2], 0.f));
  }

  // ---- Layer 1: Bbuf -> Abuf, N=128, ReLU ----
#pragma unroll
  for (int kc = 0; kc < 4; ++kc)
    af[kc] = *(const bf16x8*)(Bbuf + m * SROW + kc * 32 + quad * 8);
#pragma unroll
  for (int nc = 0; nc < 8; ++nc) {
    float bv = b1[nc * 16 + m];
    f32x4 acc = {bv, bv, bv, bv};
#pragma unroll
    for (int kc = 0; kc < 4; ++kc) {
      bf16x8 bf = *(const bf16x8*)(wp + 16384 + (nc * 4 + kc) * 512 + lane * 8);
      acc = __builtin_amdgcn_mfma_f32_16x16x32_bf16(af[kc], bf, acc, 0, 0, 0);
    }
    int col = nc * 16 + m;
#pragma unroll
    for (int r2 = 0; r2 < 4; ++r2)
      Abuf[(quad * 4 + r2) * SROW + col] = f2bf(fmaxf(acc[r2], 0.f));
  }

  // ---- Layer 2: Abuf -> registers, N=64, +b2 ----
#pragma unroll
  for (int kc = 0; kc < 4; ++kc)
    af[kc] = *(const bf16x8*)(Abuf + m * SROW + kc * 32 + quad * 8);
  f32x4 acc2[4];
#pragma unroll
  for (int nc = 0; nc < 4; ++nc) {
    float bv = b2[nc * 16 + m];
    f32x4 acc = {bv, bv, bv, bv};
#pragma unroll
    for (int kc = 0; kc < 4; ++kc) {
      bf16x8 bf = *(const bf16x8*)(wp + 32768 + (nc * 4 + kc) * 512 + lane * 8);
      acc = __builtin_amdgcn_mfma_f32_16x16x32_bf16(af[kc], bf, acc, 0, 0, 0);
    }
    acc2[nc] = acc;
  }

  // ---- LayerNorm(64) + residual; rows quad*4+r2, cols nc*16+m ----
  float s[4], ss[4];
#pragma unroll
  for (int r2 = 0; r2 < 4; ++r2) {
    float a0 = acc2[0][r2], a1 = acc2[1][r2], a2 = acc2[2][r2], a3 = acc2[3][r2];
    s[r2]  = a0 + a1 + a2 + a3;
    ss[r2] = a0 * a0 + a1 * a1 + a2 * a2 + a3 * a3;
  }
#pragma unroll
  for (int msk = 1; msk < 16; msk <<= 1) {
#pragma unroll
    for (int r2 = 0; r2 < 4; ++r2) {
      s[r2]  += __shfl_xor(s[r2], msk);
      ss[r2] += __shfl_xor(ss[r2], msk);
    }
  }
  float mu[4], rs[4];
#pragma unroll
  for (int r2 = 0; r2 < 4; ++r2) {
    mu[r2] = s[r2] * 0.015625f;
    float var = ss[r2] * 0.015625f - mu[r2] * mu[r2];
    rs[r2] = rsqrtf(var + 1e-5f);
  }
#pragma unroll
  for (int nc = 0; nc < 4; ++nc) {
    int col = nc * 16 + m;
    float g = lng[col], bb = lnb[col];
#pragma unroll
    for (int r2 = 0; r2 < 4; ++r2) {
      int node = base + quad * 4 + r2;
      float xr = x[(size_t)node * 64 + col];
      out[(size_t)node * 64 + col] =
          (acc2[nc][r2] - mu[r2]) * rs[r2] * g + bb + xr;
    }
  }
}

extern "C" void kernel_launch(void* const* d_in, const int* in_sizes, int n_in,
                              void* d_out, int out_size, void* d_ws, size_t ws_size,
                              hipStream_t stream) {
  const float* x  = (const float*)d_in[0];
  const int*   ei = (const int*)d_in[1];
  const float* ea = (const float*)d_in[2];
  const float* W0 = (const float*)d_in[3];
  const float* b0 = (const float*)d_in[4];
  const float* W1 = (const float*)d_in[5];
  const float* b1 = (const float*)d_in[6];
  const float* W2 = (const float*)d_in[7];
  const float* b2 = (const float*)d_in[8];
  const float* lg = (const float*)d_in[9];
  const float* lb = (const float*)d_in[10];
  float* out = (float*)d_out;

  const int n_edges = in_sizes[2] / DN;     // 1,200,000
  const int* col = ei + n_edges;            // edge_index[1]

  // ws layout (bytes)
  char* ws = (char*)d_ws;
  int* deg     = (int*)(ws + 0);                       // 100000
  int* row_ptr = (int*)(ws + 400000);                  // 100001
  int* cursor  = (int*)(ws + 800016);                  // 100000
  int* elist   = (int*)(ws + 1200016);                 // 1,200,000
  unsigned short* wp = (unsigned short*)(ws + 6000016); // 40960 bf16

  hipMemsetAsync(deg, 0, NNODES * sizeof(int), stream);

  hist_kernel<<<(n_edges + 255) / 256, 256, 0, stream>>>(col, deg, n_edges);
  scan_kernel<<<1, 1024, 0, stream>>>(deg, row_ptr, cursor);
  fill_kernel<<<(n_edges + 255) / 256, 256, 0, stream>>>(col, cursor, elist, n_edges);
  wprep_kernel<<<20, 256, 0, stream>>>(W0, W1, W2, wp);

  int nwaves = NNODES / 16;                 // 6250
  int nblocks = (nwaves + 3) / 4;           // 1563
  fused_mlp<<<nblocks, 256, 0, stream>>>(x, row_ptr, elist, ea, wp,
                                         b0, b1, b2, lg, lb, out);
}

// Round 3
// 643.819 us; speedup vs baseline: 2.3398x; 1.7177x over previous
//
#include <hip/hip_runtime.h>

#define NNODES 100000
#define DN 64
#define SROW 136   // act row stride in bf16 elems: 272B = 17*16B (aligned, 2-way banks)

typedef short bf16x8 __attribute__((ext_vector_type(8)));
typedef float f32x4 __attribute__((ext_vector_type(4)));

__device__ __forceinline__ unsigned short f2bf(float f) {
  unsigned int u = __float_as_uint(f);
  u = (u + 0x7fffu + ((u >> 16) & 1u)) >> 16;   // RNE
  return (unsigned short)u;
}

// ---------------------------------------------------------------------------
// CSR build: histogram -> 3-phase coalesced scan -> bucket fill
// ---------------------------------------------------------------------------
__global__ __launch_bounds__(256) void hist_kernel(const int* __restrict__ col,
                                                   int* __restrict__ deg, int n) {
  int i = blockIdx.x * 256 + threadIdx.x;
  if (i < n) atomicAdd(&deg[col[i]], 1);
}

__global__ __launch_bounds__(1024) void scan_blk(const int* __restrict__ deg,
                                                 int* __restrict__ bsum) {
  __shared__ int red[1024];
  int t = threadIdx.x;
  int i = blockIdx.x * 1024 + t;
  red[t] = (i < NNODES) ? deg[i] : 0;
  __syncthreads();
  for (int off = 512; off > 0; off >>= 1) {
    if (t < off) red[t] += red[t + off];
    __syncthreads();
  }
  if (t == 0) bsum[blockIdx.x] = red[0];
}

__global__ __launch_bounds__(128) void scan_top(int* __restrict__ bsum) {
  __shared__ int tmp[128];
  int t = threadIdx.x;
  if (t < 98) tmp[t] = bsum[t];
  __syncthreads();
  if (t == 0) {
    int run = 0;
    for (int i = 0; i < 98; ++i) { int v = tmp[i]; tmp[i] = run; run += v; }
  }
  __syncthreads();
  if (t < 98) bsum[t] = tmp[t];
}

__global__ __launch_bounds__(1024) void scan_fin(const int* __restrict__ deg,
                                                 const int* __restrict__ bsum,
                                                 int* __restrict__ row_ptr,
                                                 int* __restrict__ cursor) {
  __shared__ int ps[1024];
  int t = threadIdx.x;
  int i = blockIdx.x * 1024 + t;
  int v = (i < NNODES) ? deg[i] : 0;
  ps[t] = v;
  __syncthreads();
  for (int off = 1; off < 1024; off <<= 1) {
    int u = (t >= off) ? ps[t - off] : 0;
    __syncthreads();
    ps[t] += u;
    __syncthreads();
  }
  int excl = ps[t] - v + bsum[blockIdx.x];
  if (i < NNODES) { row_ptr[i] = excl; cursor[i] = excl; }
  if (i == NNODES - 1) row_ptr[NNODES] = excl + v;
}

__global__ __launch_bounds__(256) void fill_kernel(const int* __restrict__ col,
                                                   int* __restrict__ cursor,
                                                   int* __restrict__ elist, int n) {
  int i = blockIdx.x * 256 + threadIdx.x;
  if (i < n) {
    int pos = atomicAdd(&cursor[col[i]], 1);
    elist[pos] = i;
  }
}

// ---------------------------------------------------------------------------
// Gather: one wave per node. Lane-group g in [0,4) handles edges s+g, s+g+4,...
// each group reads a float4 x 16 lanes = one full 256B ea row per group.
// Reduce across groups via shfl, write bf16 agg row (128B).
// ---------------------------------------------------------------------------
__global__ __launch_bounds__(256) void gather_kernel(
    const int* __restrict__ row_ptr, const int* __restrict__ elist,
    const float* __restrict__ ea, unsigned short* __restrict__ aggb) {
  const int wid = threadIdx.x >> 6;
  const int lane = threadIdx.x & 63;
  const int node = blockIdx.x * 4 + wid;
  if (node >= NNODES) return;
  const int s = row_ptr[node], e = row_ptr[node + 1];
  const int g = lane >> 4;          // edge slot
  const int c4 = (lane & 15) * 4;   // channel base
  float ax = 0.f, ay = 0.f, az = 0.f, aw = 0.f;
  for (int i = s + g; i < e; i += 4) {
    int ed = elist[i];
    const float4 v = *(const float4*)(ea + (size_t)ed * 64 + c4);
    ax += v.x; ay += v.y; az += v.z; aw += v.w;
  }
  // fold the 4 groups (lanes differing in bits 4,5)
  ax += __shfl_xor(ax, 16); ay += __shfl_xor(ay, 16);
  az += __shfl_xor(az, 16); aw += __shfl_xor(aw, 16);
  ax += __shfl_xor(ax, 32); ay += __shfl_xor(ay, 32);
  az += __shfl_xor(az, 32); aw += __shfl_xor(aw, 32);
  if (g == 0) {
    ushort4 o;
    o.x = f2bf(ax); o.y = f2bf(ay); o.z = f2bf(az); o.w = f2bf(aw);
    *(ushort4*)(aggb + (size_t)node * 64 + c4) = o;
  }
}

// ---------------------------------------------------------------------------
// Weight prep: fp32 -> bf16 in exact MFMA B-fragment order.
// ---------------------------------------------------------------------------
__global__ __launch_bounds__(256) void wprep_kernel(
    const float* __restrict__ W0, const float* __restrict__ W1,
    const float* __restrict__ W2, unsigned short* __restrict__ wp) {
  int t = blockIdx.x * 256 + threadIdx.x;
  if (t >= 5120) return;
  const float* W; int c, N, dstbase;
  if (t < 2048)      { W = W0; c = t;        N = 128; dstbase = 0; }
  else if (t < 4096) { W = W1; c = t - 2048; N = 128; dstbase = 16384; }
  else               { W = W2; c = t - 4096; N = 64;  dstbase = 32768; }
  int blk = c >> 6;           // (nc*4+kc)
  int lane = c & 63;
  int nc = blk >> 2, kc = blk & 3;
  int k0 = kc * 32 + (lane >> 4) * 8;
  int n  = nc * 16 + (lane & 15);
  unsigned short* dst = wp + dstbase + blk * 512 + lane * 8;
#pragma unroll
  for (int j = 0; j < 8; ++j) dst[j] = f2bf(W[(size_t)(k0 + j) * N + n]);
}

// ---------------------------------------------------------------------------
// MLP(3 layers, bf16 MFMA) + LayerNorm + residual. One wave = 16 nodes.
// No __syncthreads: all LDS is wave-private.
// A-frag: A[m=lane&15][k=(lane>>4)*8+j]; B-frag preswizzled in wp;
// C/D: col=lane&15, row=(lane>>4)*4+reg.
// ---------------------------------------------------------------------------
__global__ __launch_bounds__(256) void fused_mlp(
    const float* __restrict__ x, const unsigned short* __restrict__ aggb,
    const unsigned short* __restrict__ wp,
    const float* __restrict__ b0, const float* __restrict__ b1,
    const float* __restrict__ b2, const float* __restrict__ lng,
    const float* __restrict__ lnb, float* __restrict__ out) {
  __shared__ unsigned short act[4 * 2 * 16 * SROW];

  const int tid = threadIdx.x;
  const int wid = tid >> 6;
  const int lane = tid & 63;
  const int gw = blockIdx.x * 4 + wid;
  if (gw >= NNODES / 16) return;           // 6250 waves exactly
  const int base = gw * 16;
  const int m = lane & 15;
  const int quad = lane >> 4;

  unsigned short* Abuf = act + (wid * 2 + 0) * 16 * SROW;
  unsigned short* Bbuf = act + (wid * 2 + 1) * 16 * SROW;

  // ---- stage concat(x, agg) as bf16 into Abuf [16 x 128] ----
#pragma unroll 4
  for (int r = 0; r < 16; ++r) {
    int node = base + r;
    Abuf[r * SROW + lane] = f2bf(x[(size_t)node * 64 + lane]);
    Abuf[r * SROW + 64 + lane] = aggb[(size_t)node * 64 + lane];
  }

  bf16x8 af[4];

  // ---- Layer 0: Abuf -> Bbuf, N=128, ReLU ----
#pragma unroll
  for (int kc = 0; kc < 4; ++kc)
    af[kc] = *(const bf16x8*)(Abuf + m * SROW + kc * 32 + quad * 8);
#pragma unroll
  for (int nc = 0; nc < 8; ++nc) {
    float bv = b0[nc * 16 + m];
    f32x4 acc = {bv, bv, bv, bv};
#pragma unroll
    for (int kc = 0; kc < 4; ++kc) {
      bf16x8 bf = *(const bf16x8*)(wp + (nc * 4 + kc) * 512 + lane * 8);
      acc = __builtin_amdgcn_mfma_f32_16x16x32_bf16(af[kc], bf, acc, 0, 0, 0);
    }
    int col = nc * 16 + m;
#pragma unroll
    for (int r2 = 0; r2 < 4; ++r2)
      Bbuf[(quad * 4 + r2) * SROW + col] = f2bf(fmaxf(acc[r2], 0.f));
  }

  // ---- Layer 1: Bbuf -> Abuf, N=128, ReLU ----
#pragma unroll
  for (int kc = 0; kc < 4; ++kc)
    af[kc] = *(const bf16x8*)(Bbuf + m * SROW + kc * 32 + quad * 8);
#pragma unroll
  for (int nc = 0; nc < 8; ++nc) {
    float bv = b1[nc * 16 + m];
    f32x4 acc = {bv, bv, bv, bv};
#pragma unroll
    for (int kc = 0; kc < 4; ++kc) {
      bf16x8 bf = *(const bf16x8*)(wp + 16384 + (nc * 4 + kc) * 512 + lane * 8);
      acc = __builtin_amdgcn_mfma_f32_16x16x32_bf16(af[kc], bf, acc, 0, 0, 0);
    }
    int col = nc * 16 + m;
#pragma unroll
    for (int r2 = 0; r2 < 4; ++r2)
      Abuf[(quad * 4 + r2) * SROW + col] = f2bf(fmaxf(acc[r2], 0.f));
  }

  // ---- Layer 2: Abuf -> registers, N=64, +b2 ----
#pragma unroll
  for (int kc = 0; kc < 4; ++kc)
    af[kc] = *(const bf16x8*)(Abuf + m * SROW + kc * 32 + quad * 8);
  f32x4 acc2[4];
#pragma unroll
  for (int nc = 0; nc < 4; ++nc) {
    float bv = b2[nc * 16 + m];
    f32x4 acc = {bv, bv, bv, bv};
#pragma unroll
    for (int kc = 0; kc < 4; ++kc) {
      bf16x8 bf = *(const bf16x8*)(wp + 32768 + (nc * 4 + kc) * 512 + lane * 8);
      acc = __builtin_amdgcn_mfma_f32_16x16x32_bf16(af[kc], bf, acc, 0, 0, 0);
    }
    acc2[nc] = acc;
  }

  // ---- LayerNorm(64) + residual; rows quad*4+r2, cols nc*16+m ----
  float s[4], ss[4];
#pragma unroll
  for (int r2 = 0; r2 < 4; ++r2) {
    float a0 = acc2[0][r2], a1 = acc2[1][r2], a2 = acc2[2][r2], a3 = acc2[3][r2];
    s[r2]  = a0 + a1 + a2 + a3;
    ss[r2] = a0 * a0 + a1 * a1 + a2 * a2 + a3 * a3;
  }
#pragma unroll
  for (int msk = 1; msk < 16; msk <<= 1) {
#pragma unroll
    for (int r2 = 0; r2 < 4; ++r2) {
      s[r2]  += __shfl_xor(s[r2], msk);
      ss[r2] += __shfl_xor(ss[r2], msk);
    }
  }
  float mu[4], rs[4];
#pragma unroll
  for (int r2 = 0; r2 < 4; ++r2) {
    mu[r2] = s[r2] * 0.015625f;
    float var = ss[r2] * 0.015625f - mu[r2] * mu[r2];
    rs[r2] = rsqrtf(var + 1e-5f);
  }
#pragma unroll
  for (int nc = 0; nc < 4; ++nc) {
    int col = nc * 16 + m;
    float g = lng[col], bb = lnb[col];
#pragma unroll
    for (int r2 = 0; r2 < 4; ++r2) {
      int node = base + quad * 4 + r2;
      float xr = x[(size_t)node * 64 + col];
      out[(size_t)node * 64 + col] =
          (acc2[nc][r2] - mu[r2]) * rs[r2] * g + bb + xr;
    }
  }
}

extern "C" void kernel_launch(void* const* d_in, const int* in_sizes, int n_in,
                              void* d_out, int out_size, void* d_ws, size_t ws_size,
                              hipStream_t stream) {
  const float* x  = (const float*)d_in[0];
  const int*   ei = (const int*)d_in[1];
  const float* ea = (const float*)d_in[2];
  const float* W0 = (const float*)d_in[3];
  const float* b0 = (const float*)d_in[4];
  const float* W1 = (const float*)d_in[5];
  const float* b1 = (const float*)d_in[6];
  const float* W2 = (const float*)d_in[7];
  const float* b2 = (const float*)d_in[8];
  const float* lg = (const float*)d_in[9];
  const float* lb = (const float*)d_in[10];
  float* out = (float*)d_out;

  const int n_edges = in_sizes[2] / DN;     // 1,200,000
  const int* col = ei + n_edges;            // edge_index[1]

  // ws layout (bytes)
  char* ws = (char*)d_ws;
  int* deg     = (int*)(ws + 0);                        // 100000 ints
  int* row_ptr = (int*)(ws + 400000);                   // 100001 ints
  int* cursor  = (int*)(ws + 800016);                   // 100000 ints
  int* elist   = (int*)(ws + 1200016);                  // 1,200,000 ints
  unsigned short* wp = (unsigned short*)(ws + 6000016); // 40960 bf16
  int* bsum    = (int*)(ws + 6082000);                  // 98 ints
  unsigned short* aggb = (unsigned short*)(ws + 6082512); // 6.4M bf16

  hipMemsetAsync(deg, 0, NNODES * sizeof(int), stream);

  hist_kernel<<<(n_edges + 255) / 256, 256, 0, stream>>>(col, deg, n_edges);
  scan_blk<<<98, 1024, 0, stream>>>(deg, bsum);
  scan_top<<<1, 128, 0, stream>>>(bsum);
  scan_fin<<<98, 1024, 0, stream>>>(deg, bsum, row_ptr, cursor);
  fill_kernel<<<(n_edges + 255) / 256, 256, 0, stream>>>(col, cursor, elist, n_edges);
  wprep_kernel<<<20, 256, 0, stream>>>(W0, W1, W2, wp);

  gather_kernel<<<(NNODES + 3) / 4, 256, 0, stream>>>(row_ptr, elist, ea, aggb);

  int nblocks = (NNODES / 16 + 3) / 4;      // 1563
  fused_mlp<<<nblocks, 256, 0, stream>>>(x, aggb, wp, b0, b1, b2, lg, lb, out);
}

// Round 4
// 583.968 us; speedup vs baseline: 2.5796x; 1.1025x over previous
//
#include <hip/hip_runtime.h>

#define NNODES 100000
#define DN 64
#define SROW 136   // act row stride in bf16 elems: 272B = 17*16B (aligned, 2-way banks)

typedef short bf16x8 __attribute__((ext_vector_type(8)));
typedef float f32x4 __attribute__((ext_vector_type(4)));

__device__ __forceinline__ unsigned short f2bf(float f) {
  unsigned int u = __float_as_uint(f);
  u = (u + 0x7fffu + ((u >> 16) & 1u)) >> 16;   // RNE
  return (unsigned short)u;
}
__device__ __forceinline__ float bf2f(unsigned short h) {
  return __uint_as_float(((unsigned int)h) << 16);
}

// ---------------------------------------------------------------------------
// CSR build: histogram -> 3-phase coalesced scan
// ---------------------------------------------------------------------------
__global__ __launch_bounds__(256) void hist_kernel(const int* __restrict__ col,
                                                   int* __restrict__ deg, int n) {
  int i = blockIdx.x * 256 + threadIdx.x;
  if (i < n) atomicAdd(&deg[col[i]], 1);
}

__global__ __launch_bounds__(1024) void scan_blk(const int* __restrict__ deg,
                                                 int* __restrict__ bsum) {
  __shared__ int red[1024];
  int t = threadIdx.x;
  int i = blockIdx.x * 1024 + t;
  red[t] = (i < NNODES) ? deg[i] : 0;
  __syncthreads();
  for (int off = 512; off > 0; off >>= 1) {
    if (t < off) red[t] += red[t + off];
    __syncthreads();
  }
  if (t == 0) bsum[blockIdx.x] = red[0];
}

__global__ __launch_bounds__(128) void scan_top(int* __restrict__ bsum) {
  __shared__ int tmp[128];
  int t = threadIdx.x;
  if (t < 98) tmp[t] = bsum[t];
  __syncthreads();
  if (t == 0) {
    int run = 0;
    for (int i = 0; i < 98; ++i) { int v = tmp[i]; tmp[i] = run; run += v; }
  }
  __syncthreads();
  if (t < 98) bsum[t] = tmp[t];
}

__global__ __launch_bounds__(1024) void scan_fin(const int* __restrict__ deg,
                                                 const int* __restrict__ bsum,
                                                 int* __restrict__ row_ptr,
                                                 int* __restrict__ cursor) {
  __shared__ int ps[1024];
  int t = threadIdx.x;
  int i = blockIdx.x * 1024 + t;
  int v = (i < NNODES) ? deg[i] : 0;
  ps[t] = v;
  __syncthreads();
  for (int off = 1; off < 1024; off <<= 1) {
    int u = (t >= off) ? ps[t - off] : 0;
    __syncthreads();
    ps[t] += u;
    __syncthreads();
  }
  int excl = ps[t] - v + bsum[blockIdx.x];
  if (i < NNODES) { row_ptr[i] = excl; cursor[i] = excl; }
  if (i == NNODES - 1) row_ptr[NNODES] = excl + v;
}

// ---------------------------------------------------------------------------
// Fill+convert: copy each edge row (as bf16) to its destination-sorted slot.
// 16 threads per edge: coalesced float4 read (256B/row), 8B/lane write to a
// 128B-aligned full-line destination row. One atomic per edge (sub-lane 0).
// ---------------------------------------------------------------------------
__global__ __launch_bounds__(256) void fillconv_kernel(
    const int* __restrict__ col, const float* __restrict__ ea,
    int* __restrict__ cursor, unsigned short* __restrict__ sorted, int n) {
  int t = blockIdx.x * 256 + threadIdx.x;
  int e = t >> 4;
  if (e >= n) return;
  const int sub = t & 15;
  const int lane = threadIdx.x & 63;
  int d = col[e];
  int pos = 0;
  if (sub == 0) pos = atomicAdd(&cursor[d], 1);
  pos = __shfl(pos, lane & 48);            // broadcast from sub==0 of this group
  float4 v = *(const float4*)(ea + (size_t)e * 64 + sub * 4);
  ushort4 o;
  o.x = f2bf(v.x); o.y = f2bf(v.y); o.z = f2bf(v.z); o.w = f2bf(v.w);
  *(ushort4*)(sorted + (size_t)pos * 64 + sub * 4) = o;
}

// ---------------------------------------------------------------------------
// Gather: dense segmented sum over consecutive sorted rows. One wave per node;
// one dwordx4 wave-load covers 8 rows (1KB); lane l handles row (l>>3),
// channels (l&7)*8..+7. Fold rows with 3 shfl_xor rounds; lanes 0..7 write
// the bf16 agg row (16B each).
// ---------------------------------------------------------------------------
__global__ __launch_bounds__(256) void gather_kernel(
    const int* __restrict__ row_ptr, const unsigned short* __restrict__ sorted,
    unsigned short* __restrict__ aggb) {
  const int wid = threadIdx.x >> 6;
  const int lane = threadIdx.x & 63;
  const int node = blockIdx.x * 4 + wid;
  if (node >= NNODES) return;
  const int s = row_ptr[node], e = row_ptr[node + 1];
  const int ch0 = (lane & 7) * 8;
  float acc[8];
#pragma unroll
  for (int k = 0; k < 8; ++k) acc[k] = 0.f;
  for (int j = s + (lane >> 3); j < e; j += 8) {
    bf16x8 v = *(const bf16x8*)(sorted + (size_t)j * 64 + ch0);
#pragma unroll
    for (int k = 0; k < 8; ++k) acc[k] += bf2f((unsigned short)v[k]);
  }
#pragma unroll
  for (int msk = 8; msk < 64; msk <<= 1)
#pragma unroll
    for (int k = 0; k < 8; ++k) acc[k] += __shfl_xor(acc[k], msk);
  if (lane < 8) {
    bf16x8 o;
#pragma unroll
    for (int k = 0; k < 8; ++k) o[k] = (short)f2bf(acc[k]);
    *(bf16x8*)(aggb + (size_t)node * 64 + lane * 8) = o;
  }
}

// ---------------------------------------------------------------------------
// Weight prep: fp32 -> bf16 in exact MFMA B-fragment order.
// ---------------------------------------------------------------------------
__global__ __launch_bounds__(256) void wprep_kernel(
    const float* __restrict__ W0, const float* __restrict__ W1,
    const float* __restrict__ W2, unsigned short* __restrict__ wp) {
  int t = blockIdx.x * 256 + threadIdx.x;
  if (t >= 5120) return;
  const float* W; int c, N, dstbase;
  if (t < 2048)      { W = W0; c = t;        N = 128; dstbase = 0; }
  else if (t < 4096) { W = W1; c = t - 2048; N = 128; dstbase = 16384; }
  else               { W = W2; c = t - 4096; N = 64;  dstbase = 32768; }
  int blk = c >> 6;           // (nc*4+kc)
  int lane = c & 63;
  int nc = blk >> 2, kc = blk & 3;
  int k0 = kc * 32 + (lane >> 4) * 8;
  int n  = nc * 16 + (lane & 15);
  unsigned short* dst = wp + dstbase + blk * 512 + lane * 8;
#pragma unroll
  for (int j = 0; j < 8; ++j) dst[j] = f2bf(W[(size_t)(k0 + j) * N + n]);
}

// ---------------------------------------------------------------------------
// MLP(3 layers, bf16 MFMA) + LayerNorm + residual. One wave = 16 nodes.
// No __syncthreads: all LDS is wave-private.
// A-frag: A[m=lane&15][k=(lane>>4)*8+j]; B-frag preswizzled in wp;
// C/D: col=lane&15, row=(lane>>4)*4+reg.
// ---------------------------------------------------------------------------
__global__ __launch_bounds__(256) void fused_mlp(
    const float* __restrict__ x, const unsigned short* __restrict__ aggb,
    const unsigned short* __restrict__ wp,
    const float* __restrict__ b0, const float* __restrict__ b1,
    const float* __restrict__ b2, const float* __restrict__ lng,
    const float* __restrict__ lnb, float* __restrict__ out) {
  __shared__ unsigned short act[4 * 2 * 16 * SROW];

  const int tid = threadIdx.x;
  const int wid = tid >> 6;
  const int lane = tid & 63;
  const int gw = blockIdx.x * 4 + wid;
  if (gw >= NNODES / 16) return;           // 6250 waves exactly
  const int base = gw * 16;
  const int m = lane & 15;
  const int quad = lane >> 4;

  unsigned short* Abuf = act + (wid * 2 + 0) * 16 * SROW;
  unsigned short* Bbuf = act + (wid * 2 + 1) * 16 * SROW;

  // ---- stage concat(x, agg) as bf16 into Abuf [16 x 128] ----
#pragma unroll 4
  for (int r = 0; r < 16; ++r) {
    int node = base + r;
    Abuf[r * SROW + lane] = f2bf(x[(size_t)node * 64 + lane]);
    Abuf[r * SROW + 64 + lane] = aggb[(size_t)node * 64 + lane];
  }

  bf16x8 af[4];

  // ---- Layer 0: Abuf -> Bbuf, N=128, ReLU ----
#pragma unroll
  for (int kc = 0; kc < 4; ++kc)
    af[kc] = *(const bf16x8*)(Abuf + m * SROW + kc * 32 + quad * 8);
#pragma unroll
  for (int nc = 0; nc < 8; ++nc) {
    float bv = b0[nc * 16 + m];
    f32x4 acc = {bv, bv, bv, bv};
#pragma unroll
    for (int kc = 0; kc < 4; ++kc) {
      bf16x8 bf = *(const bf16x8*)(wp + (nc * 4 + kc) * 512 + lane * 8);
      acc = __builtin_amdgcn_mfma_f32_16x16x32_bf16(af[kc], bf, acc, 0, 0, 0);
    }
    int col = nc * 16 + m;
#pragma unroll
    for (int r2 = 0; r2 < 4; ++r2)
      Bbuf[(quad * 4 + r2) * SROW + col] = f2bf(fmaxf(acc[r2], 0.f));
  }

  // ---- Layer 1: Bbuf -> Abuf, N=128, ReLU ----
#pragma unroll
  for (int kc = 0; kc < 4; ++kc)
    af[kc] = *(const bf16x8*)(Bbuf + m * SROW + kc * 32 + quad * 8);
#pragma unroll
  for (int nc = 0; nc < 8; ++nc) {
    float bv = b1[nc * 16 + m];
    f32x4 acc = {bv, bv, bv, bv};
#pragma unroll
    for (int kc = 0; kc < 4; ++kc) {
      bf16x8 bf = *(const bf16x8*)(wp + 16384 + (nc * 4 + kc) * 512 + lane * 8);
      acc = __builtin_amdgcn_mfma_f32_16x16x32_bf16(af[kc], bf, acc, 0, 0, 0);
    }
    int col = nc * 16 + m;
#pragma unroll
    for (int r2 = 0; r2 < 4; ++r2)
      Abuf[(quad * 4 + r2) * SROW + col] = f2bf(fmaxf(acc[r2], 0.f));
  }

  // ---- Layer 2: Abuf -> registers, N=64, +b2 ----
#pragma unroll
  for (int kc = 0; kc < 4; ++kc)
    af[kc] = *(const bf16x8*)(Abuf + m * SROW + kc * 32 + quad * 8);
  f32x4 acc2[4];
#pragma unroll
  for (int nc = 0; nc < 4; ++nc) {
    float bv = b2[nc * 16 + m];
    f32x4 acc = {bv, bv, bv, bv};
#pragma unroll
    for (int kc = 0; kc < 4; ++kc) {
      bf16x8 bf = *(const bf16x8*)(wp + 32768 + (nc * 4 + kc) * 512 + lane * 8);
      acc = __builtin_amdgcn_mfma_f32_16x16x32_bf16(af[kc], bf, acc, 0, 0, 0);
    }
    acc2[nc] = acc;
  }

  // ---- LayerNorm(64) + residual; rows quad*4+r2, cols nc*16+m ----
  float s[4], ss[4];
#pragma unroll
  for (int r2 = 0; r2 < 4; ++r2) {
    float a0 = acc2[0][r2], a1 = acc2[1][r2], a2 = acc2[2][r2], a3 = acc2[3][r2];
    s[r2]  = a0 + a1 + a2 + a3;
    ss[r2] = a0 * a0 + a1 * a1 + a2 * a2 + a3 * a3;
  }
#pragma unroll
  for (int msk = 1; msk < 16; msk <<= 1) {
#pragma unroll
    for (int r2 = 0; r2 < 4; ++r2) {
      s[r2]  += __shfl_xor(s[r2], msk);
      ss[r2] += __shfl_xor(ss[r2], msk);
    }
  }
  float mu[4], rs[4];
#pragma unroll
  for (int r2 = 0; r2 < 4; ++r2) {
    mu[r2] = s[r2] * 0.015625f;
    float var = ss[r2] * 0.015625f - mu[r2] * mu[r2];
    rs[r2] = rsqrtf(var + 1e-5f);
  }
#pragma unroll
  for (int nc = 0; nc < 4; ++nc) {
    int col = nc * 16 + m;
    float g = lng[col], bb = lnb[col];
#pragma unroll
    for (int r2 = 0; r2 < 4; ++r2) {
      int node = base + quad * 4 + r2;
      float xr = x[(size_t)node * 64 + col];
      out[(size_t)node * 64 + col] =
          (acc2[nc][r2] - mu[r2]) * rs[r2] * g + bb + xr;
    }
  }
}

extern "C" void kernel_launch(void* const* d_in, const int* in_sizes, int n_in,
                              void* d_out, int out_size, void* d_ws, size_t ws_size,
                              hipStream_t stream) {
  const float* x  = (const float*)d_in[0];
  const int*   ei = (const int*)d_in[1];
  const float* ea = (const float*)d_in[2];
  const float* W0 = (const float*)d_in[3];
  const float* b0 = (const float*)d_in[4];
  const float* W1 = (const float*)d_in[5];
  const float* b1 = (const float*)d_in[6];
  const float* W2 = (const float*)d_in[7];
  const float* b2 = (const float*)d_in[8];
  const float* lg = (const float*)d_in[9];
  const float* lb = (const float*)d_in[10];
  float* out = (float*)d_out;

  const int n_edges = in_sizes[2] / DN;     // 1,200,000
  const int* col = ei + n_edges;            // edge_index[1]

  // ws layout (bytes)
  char* ws = (char*)d_ws;
  int* deg     = (int*)(ws + 0);                          // 100000 ints
  int* row_ptr = (int*)(ws + 400000);                     // 100001 ints
  int* cursor  = (int*)(ws + 800016);                     // 100000 ints
  int* bsum    = (int*)(ws + 1200016);                    // 98 ints
  unsigned short* wp   = (unsigned short*)(ws + 1200512); // 40960 bf16 (80KB)
  unsigned short* aggb = (unsigned short*)(ws + 1282432); // 6.4M bf16 (12.8MB)
  unsigned short* sorted = (unsigned short*)(ws + 14083072); // 76.8M bf16 (153.6MB)

  hipMemsetAsync(deg, 0, NNODES * sizeof(int), stream);

  hist_kernel<<<(n_edges + 255) / 256, 256, 0, stream>>>(col, deg, n_edges);
  scan_blk<<<98, 1024, 0, stream>>>(deg, bsum);
  scan_top<<<1, 128, 0, stream>>>(bsum);
  scan_fin<<<98, 1024, 0, stream>>>(deg, bsum, row_ptr, cursor);
  wprep_kernel<<<20, 256, 0, stream>>>(W0, W1, W2, wp);

  fillconv_kernel<<<(n_edges * 16 + 255) / 256, 256, 0, stream>>>(
      col, ea, cursor, sorted, n_edges);

  gather_kernel<<<(NNODES + 3) / 4, 256, 0, stream>>>(row_ptr, sorted, aggb);

  int nblocks = (NNODES / 16 + 3) / 4;      // 1563
  fused_mlp<<<nblocks, 256, 0, stream>>>(x, aggb, wp, b0, b1, b2, lg, lb, out);
}